// Round 5
// baseline (268.424 us; speedup 1.0000x reference)
//
#include <hip/hip_runtime.h>
#include <hip/hip_bf16.h>

#define N_   16
#define CI_  256
#define CO_  256
#define D_   4096
#define DO_  8192
#define KTOT 768            // 3 taps (j) x 256 ci
#define WT_ELEMS (512 * KTOT)

typedef short frag8 __attribute__((ext_vector_type(8)));   // 8 bf16 (4 VGPR)
typedef float facc4 __attribute__((ext_vector_type(4)));   // 4 f32 acc

static __device__ __forceinline__ unsigned short f2bf(float f) {
    union { __hip_bfloat16 h; unsigned short u; } cv;
    cv.h = __float2bfloat16(f);
    return cv.u;
}

static __device__ __forceinline__ unsigned int pack2(float lo, float hi) {
    return (unsigned int)f2bf(lo) | ((unsigned int)f2bf(hi) << 16);
}

static __device__ __forceinline__ void async16(unsigned short* lds, const unsigned short* g) {
    __builtin_amdgcn_global_load_lds(
        (const __attribute__((address_space(1))) unsigned int*)g,
        (__attribute__((address_space(3))) unsigned int*)lds, 16, 0, 0);
}

// opaque LDS read: no "memory" clobber -> no compiler alias edge to in-flight
// global_load_lds writes (no auto vmcnt(0) drains).
#define DSR_(dst, addr, litstr) \
    asm volatile("ds_read_b128 %0, %1 offset:" litstr : "=&v"(dst) : "v"(addr))

// ---------------- prep: effective bf16 weights ---------------------------
// Wt[m = co*2+phase][k = j*256 + ci]; j=0 -> x[t-1], j=1 -> x[t], j=2 -> x[t+1]
__global__ __launch_bounds__(256) void prep_wt(const float* __restrict__ w,
                                               unsigned short* __restrict__ Wt) {
    const int ci = threadIdx.x;
    const int co = blockIdx.x;
    const float* wp = w + ((size_t)co * CI_ + ci) * 3;
    const float w0 = wp[0], w1 = wp[1], w2 = wp[2];
    const float e0 = 0.25f * w1 + 0.75f * w0;
    const float e1 = 0.75f * w2 + 0.75f * w1 + 0.25f * w0;
    const float e2 = 0.25f * w2;
    const float o0 = 0.25f * w0;
    const float o1 = 0.25f * w2 + 0.75f * w1 + 0.75f * w0;
    const float o2 = 0.75f * w2 + 0.25f * w1;
    unsigned short* pe = Wt + (size_t)(co * 2 + 0) * KTOT;
    unsigned short* po = Wt + (size_t)(co * 2 + 1) * KTOT;
    pe[0 * 256 + ci] = f2bf(e0); pe[1 * 256 + ci] = f2bf(e1); pe[2 * 256 + ci] = f2bf(e2);
    po[0 * 256 + ci] = f2bf(o0); po[1 * 256 + ci] = f2bf(o1); po[2 * 256 + ci] = f2bf(o2);
}

// ---------------- fused main: 256m x 256t bf16 MFMA GEMM -----------------
// C[m][t] = sum_k Wt[m][k] * x[ci(k)][t + j(k) - 1].  B staged in-LDS directly
// from x (transpose fused; prep_xt2 eliminated): Bx[258 rows][64 ci] bf16,
// row r holds x[g*64..+63][bt0 - 1 + r]; one stage per ci-group g, reused by
// all 3 taps (tap j = row offset +j).  K-order: g-major, j-minor; 12 K-tiles
// of 64 k.  A path identical to verified r4 (slot-XOR layout, 0 conflicts).
// Phases: 4/K-tile, lgkmcnt(0) BEFORE each barrier (all waves' LDS reads
// provably drained before any region is re-written -> 1 barrier/phase).
// vmcnt FIFO (per thread): A stg = 4 loads/K-tile @Q3; B = 10 loads @ j0-Q3,
// drained @ j2-Q3 (immediates 14/14/4, uniform incl. dummy g=3 / tail kts).
__global__ __launch_bounds__(512, 2) void gemm_fused(
    const unsigned short* __restrict__ Wt, const float* __restrict__ x,
    const float* __restrict__ bias, float* __restrict__ out)
{
    __shared__ __align__(16) unsigned short SL[49280];  // 64KB A dbuf + 33KB Bx

    const int tid  = threadIdx.x;
    const int lane = tid & 63;
    const int wid  = tid >> 6;          // 0..7
    const int quad = lane >> 4;
    const int l16  = lane & 15;

    const int bt0 = blockIdx.x * 256;   // t tile
    const int bm0 = blockIdx.y * 256;   // m tile (m = co*2+phase)
    const int n   = blockIdx.z;
    const float* xn = x + (size_t)n * CI_ * D_;

    // ---- A staging (r4-verified) ----
    const int srow = wid * 16 + (lane >> 2);           // 0..127 row in m-half
    const int cg   = (lane & 3) ^ ((lane >> 3) & 3);   // slot-XOR
    const unsigned short* sA = Wt + (size_t)(bm0 + srow) * KTOT + cg * 8;

    // ---- B staging thread roles ----
    const int cp = tid >> 4;        // 0..31 ci-pair
    const int tq = tid & 15;        // 16-t chunk selector per s

    // ---- fragment read bases ----
    const int swz = quad ^ ((l16 >> 1) & 3);
    const int mh  = wid & 1;
    const int wm  = mh * 128;
    const int wt  = ((wid >> 1) & 3) * 64;
    const unsigned base = (unsigned)(size_t)&SL[0];
    const unsigned aB  = base + (unsigned)(mh * 16384 + l16 * 64 + swz * 16);
    const unsigned bxb = base + 65536u;   // Bx byte offset

    facc4 acc[8][4] = {};

    // K-tile kt -> source k offset (j*256 + g*64); 12,13 clamped (dummy)
    const int KOFF[14] = {0,256,512, 64,320,576, 128,384,640, 192,448,704, 704,704};

    // stage one K-tile of A (4 loads/thread: 2 mh x 2 kh)
    #define STAGE_A(kt2, koff) do { const int par_ = (kt2) & 1;                     \
        async16(SL + par_*16384 + 0*8192 + 0*4096 + wid*512, sA + (size_t)0*128*KTOT + (koff) + 0);  \
        async16(SL + par_*16384 + 0*8192 + 1*4096 + wid*512, sA + (size_t)0*128*KTOT + (koff) + 32); \
        async16(SL + par_*16384 + 1*8192 + 0*4096 + wid*512, sA + (size_t)1*128*KTOT + (koff) + 0);  \
        async16(SL + par_*16384 + 1*8192 + 1*4096 + wid*512, sA + (size_t)1*128*KTOT + (koff) + 32); \
    } while (0)

    // issue B global loads for ci-group g2 (10 VMEM/thread, uniform)
    float4 va[4], vb[4];
    float  h0 = 0.f, h1 = 0.f;
    #define BLOAD(g2) do {                                                          \
        const float* bsrc = xn + (size_t)((g2)*64 + cp*2) * D_ + bt0;               \
        _Pragma("unroll") for (int s_ = 0; s_ < 4; ++s_) {                          \
            va[s_] = *(const float4*)(bsrc + s_*64 + tq*4);                         \
            vb[s_] = *(const float4*)(bsrc + D_ + s_*64 + tq*4); }                  \
        { int cph = tid & 31; int hrow = (tid & 32) ? 257 : 0;                      \
          int th  = bt0 - 1 + hrow;                                                 \
          int tcl = th < 0 ? 0 : (th > D_-1 ? D_-1 : th);                           \
          const float* hsrc = xn + (size_t)((g2)*64 + cph*2) * D_ + tcl;            \
          h0 = hsrc[0]; h1 = hsrc[D_]; }                                            \
    } while (0)

    // pack + write staged B into Bx (rows 1..256 + 2 halo rows)
    #define BWRITE() do {                                                           \
        _Pragma("unroll") for (int s_ = 0; s_ < 4; ++s_)                            \
        _Pragma("unroll") for (int e_ = 0; e_ < 4; ++e_) {                          \
            int row = s_*64 + tq*4 + 1 + e_;                                        \
            unsigned pc = (((unsigned)(cp >> 2) ^ (unsigned)(row & 7)) << 2) | (unsigned)(cp & 3); \
            *(unsigned*)((char*)SL + 65536u + (unsigned)row*128u + pc*4u) =         \
                pack2(((const float*)&va[s_])[e_], ((const float*)&vb[s_])[e_]); }  \
        if (tid < 64) {                                                             \
            int cph = tid & 31; int hrow = (tid & 32) ? 257 : 0;                    \
            int th  = bt0 - 1 + hrow;                                               \
            int ok  = (th >= 0) && (th < D_);                                       \
            unsigned pc = (((unsigned)(cph >> 2) ^ (unsigned)(hrow & 7)) << 2) | (unsigned)(cph & 3); \
            *(unsigned*)((char*)SL + 65536u + (unsigned)hrow*128u + pc*4u) =        \
                ok ? pack2(h0, h1) : 0u; }                                          \
    } while (0)

    #define MM_(M, T, AF)                                                                        \
        acc[M][T] = __builtin_amdgcn_mfma_f32_16x16x32_bf16(AF[0], b[T][0], acc[M][T], 0, 0, 0); \
        acc[M][T] = __builtin_amdgcn_mfma_f32_16x16x32_bf16(AF[1], b[T][1], acc[M][T], 0, 0, 0);

    #define PHASE_SYNC() do {                                        \
        asm volatile("s_waitcnt lgkmcnt(0)" ::: "memory");           \
        __builtin_amdgcn_sched_barrier(0);                           \
        __builtin_amdgcn_s_barrier();                                \
        __builtin_amdgcn_sched_barrier(0);                           \
    } while (0)

    // ---- prologue: B(g=0) + A kt0,kt1; build Bx[0]; gate kt0 ----
    BLOAD(0);
    asm volatile("" ::: "memory");          // keep B loads before A stages (FIFO)
    STAGE_A(0, KOFF[0]);
    STAGE_A(1, KOFF[1]);
    asm volatile("s_waitcnt vmcnt(8)" ::: "memory");   // drain B10 (18 -> 8)
    BWRITE();
    asm volatile("s_waitcnt vmcnt(4)" ::: "memory");   // drain stg(0)
    PHASE_SYNC();

    #pragma unroll
    for (int kt = 0; kt < 12; ++kt) {
        const int j = kt % 3;
        const unsigned au = aB + (unsigned)((kt & 1) * 32768);
        const int rowc = wt + l16 + j;
        const unsigned rb = bxb + (unsigned)rowc * 128u;
        const unsigned bk0 = rb + (unsigned)(((quad    ) ^ (rowc & 7)) << 4);
        const unsigned bk1 = rb + (unsigned)(((quad + 4) ^ (rowc & 7)) << 4);

        frag8 aLo[4][2], aHi[4][2], b[4][2];

        // ---- Q0: read aLo + b[0..1]; MFMA m0-3 x t0-1
        DSR_(aLo[0][0], au, "0");    DSR_(aLo[0][1], au, "8192");
        DSR_(aLo[1][0], au, "1024"); DSR_(aLo[1][1], au, "9216");
        DSR_(aLo[2][0], au, "2048"); DSR_(aLo[2][1], au, "10240");
        DSR_(aLo[3][0], au, "3072"); DSR_(aLo[3][1], au, "11264");
        DSR_(b[0][0], bk0, "0");     DSR_(b[0][1], bk1, "0");
        DSR_(b[1][0], bk0, "2048");  DSR_(b[1][1], bk1, "2048");
        PHASE_SYNC();
        __builtin_amdgcn_s_setprio(1);
        MM_(0,0,aLo[0]) MM_(1,0,aLo[1]) MM_(2,0,aLo[2]) MM_(3,0,aLo[3])
        MM_(0,1,aLo[0]) MM_(1,1,aLo[1]) MM_(2,1,aLo[2]) MM_(3,1,aLo[3])
        __builtin_amdgcn_s_setprio(0);

        // ---- Q1: read b[2..3]; MFMA m0-3 x t2-3  (last Bx reads of this kt)
        DSR_(b[2][0], bk0, "4096");  DSR_(b[2][1], bk1, "4096");
        DSR_(b[3][0], bk0, "6144");  DSR_(b[3][1], bk1, "6144");
        PHASE_SYNC();
        __builtin_amdgcn_s_setprio(1);
        MM_(0,2,aLo[0]) MM_(1,2,aLo[1]) MM_(2,2,aLo[2]) MM_(3,2,aLo[3])
        MM_(0,3,aLo[0]) MM_(1,3,aLo[1]) MM_(2,3,aLo[2]) MM_(3,3,aLo[3])
        __builtin_amdgcn_s_setprio(0);

        // ---- Q2: read aHi; MFMA m4-7 x t0-1  (last A-dbuf reads of this kt)
        DSR_(aHi[0][0], au, "4096"); DSR_(aHi[0][1], au, "12288");
        DSR_(aHi[1][0], au, "5120"); DSR_(aHi[1][1], au, "13312");
        DSR_(aHi[2][0], au, "6144"); DSR_(aHi[2][1], au, "14336");
        DSR_(aHi[3][0], au, "7168"); DSR_(aHi[3][1], au, "15360");
        PHASE_SYNC();
        __builtin_amdgcn_s_setprio(1);
        MM_(4,0,aHi[0]) MM_(5,0,aHi[1]) MM_(6,0,aHi[2]) MM_(7,0,aHi[3])
        MM_(4,1,aHi[0]) MM_(5,1,aHi[1]) MM_(6,1,aHi[2]) MM_(7,1,aHi[3])
        __builtin_amdgcn_s_setprio(0);

        // ---- Q3: B drain/write (j2) | A stage kt+2 | B issue (j0) | gate | MFMA
        if (j == 2) {
            asm volatile("s_waitcnt vmcnt(4)" ::: "memory");  // drain B10, keep stg(kt+1)
            BWRITE();                                         // Bx[g+1] (all reads done @Q1)
        }
        STAGE_A(kt + 2, KOFF[kt + 2]);                        // writes dbuf[kt&1]: reads done @Q2
        if (j == 0) BLOAD(((kt / 3) + 1) & 3);                // 10 loads (dummy at g=3)
        if (j == 2) { asm volatile("s_waitcnt vmcnt(4)"  ::: "memory"); }  // drain stg(kt+1)
        else        { asm volatile("s_waitcnt vmcnt(14)" ::: "memory"); }  // drain stg(kt+1)
        PHASE_SYNC();
        __builtin_amdgcn_s_setprio(1);
        MM_(4,2,aHi[0]) MM_(5,2,aHi[1]) MM_(6,2,aHi[2]) MM_(7,2,aHi[3])
        MM_(4,3,aHi[0]) MM_(5,3,aHi[1]) MM_(6,3,aHi[2]) MM_(7,3,aHi[3])
        __builtin_amdgcn_s_setprio(0);
    }
    asm volatile("s_waitcnt vmcnt(0)" ::: "memory");

    #undef MM_
    #undef PHASE_SYNC
    #undef STAGE_A
    #undef BLOAD
    #undef BWRITE

    // epilogue: D row = quad*4+reg (= m), col = l16 (= t); regs span 2 co x 2 phase
    #pragma unroll
    for (int m8 = 0; m8 < 8; ++m8) {
        int m0  = bm0 + wm + m8 * 16 + quad * 4;
        int co0 = m0 >> 1;
        float b0 = bias[co0];
        float b1 = bias[co0 + 1];
        #pragma unroll
        for (int t4 = 0; t4 < 4; ++t4) {
            int t = bt0 + wt + t4 * 16 + l16;
            facc4 v = acc[m8][t4];
            float* p0 = out + ((size_t)(n * CO_ + co0)) * DO_ + 2 * t;
            float* p1 = p0 + DO_;
            *(float2*)p0 = make_float2(v.x + b0, v.y + b0);
            *(float2*)p1 = make_float2(v.z + b1, v.w + b1);
        }
    }
}

// ---------------- fallback (round-1 verified kernel) ---------------------
__global__ __launch_bounds__(256) void upconv_fir_f32(
    const float* __restrict__ x, const float* __restrict__ w,
    const float* __restrict__ bias, float* __restrict__ out)
{
    __shared__ float ws[CI_][4];
    const int tid = threadIdx.x;
    const int co  = blockIdx.y;
    const int n   = blockIdx.z;
    {
        const float* wc = w + (size_t)co * CI_ * 3;
        ws[tid][0] = wc[tid * 3 + 0];
        ws[tid][1] = wc[tid * 3 + 1];
        ws[tid][2] = wc[tid * 3 + 2];
        ws[tid][3] = 0.f;
    }
    __syncthreads();
    const int t0 = (blockIdx.x * 256 + tid) * 8;
    const float* xn = x + (size_t)n * CI_ * D_;
    float s[10], g[9];
    #pragma unroll
    for (int k = 0; k < 10; ++k) s[k] = 0.f;
    #pragma unroll
    for (int k = 0; k < 9; ++k) g[k] = 0.f;
    #pragma unroll 2
    for (int ci = 0; ci < CI_; ++ci) {
        const float* xr = xn + ci * D_;
        float4 va = *(const float4*)(xr + t0);
        float4 vb = *(const float4*)(xr + t0 + 4);
        float  xm = (t0 > 0)      ? xr[t0 - 1] : 0.f;
        float  xp = (t0 + 8 < D_) ? xr[t0 + 8] : 0.f;
        float4 wv = *(const float4*)(&ws[ci][0]);
        const float w0 = wv.x, w1 = wv.y, w2 = wv.z;
        float xa[10];
        xa[0] = xm; xa[1] = va.x; xa[2] = va.y; xa[3] = va.z; xa[4] = va.w;
        xa[5] = vb.x; xa[6] = vb.y; xa[7] = vb.z; xa[8] = vb.w; xa[9] = xp;
        #pragma unroll
        for (int k = 0; k < 10; ++k) s[k] += w1 * xa[k];
        #pragma unroll
        for (int k = 0; k < 9; ++k)  g[k] += w0 * xa[k] + w2 * xa[k + 1];
    }
    const float b = bias[co];
    float o16[16];
    #pragma unroll
    for (int tt = 0; tt < 8; ++tt) {
        o16[2 * tt]     = 0.25f * (s[tt] + g[tt + 1]) + 0.75f * (g[tt] + s[tt + 1]) + b;
        o16[2 * tt + 1] = 0.25f * (g[tt] + s[tt + 2]) + 0.75f * (s[tt + 1] + g[tt + 1]) + b;
    }
    float* ob = out + ((size_t)n * CO_ + co) * DO_ + 2 * t0;
    *(float4*)(ob + 0)  = make_float4(o16[0],  o16[1],  o16[2],  o16[3]);
    *(float4*)(ob + 4)  = make_float4(o16[4],  o16[5],  o16[6],  o16[7]);
    *(float4*)(ob + 8)  = make_float4(o16[8],  o16[9],  o16[10], o16[11]);
    *(float4*)(ob + 12) = make_float4(o16[12], o16[13], o16[14], o16[15]);
}

extern "C" void kernel_launch(void* const* d_in, const int* in_sizes, int n_in,
                              void* d_out, int out_size, void* d_ws, size_t ws_size,
                              hipStream_t stream) {
    const float* x  = (const float*)d_in[0];
    const float* w  = (const float*)d_in[1];
    const float* b  = (const float*)d_in[2];
    float* out      = (float*)d_out;

    const size_t need = (size_t)WT_ELEMS * 2;
    if (ws_size >= need) {
        unsigned short* Wt = (unsigned short*)d_ws;
        prep_wt<<<dim3(CO_), 256, 0, stream>>>(w, Wt);
        gemm_fused<<<dim3(D_ / 256, 2, N_), 512, 0, stream>>>(Wt, x, b, out);
    } else {
        upconv_fir_f32<<<dim3(2, CO_, N_), 256, 0, stream>>>(x, w, b, out);
    }
}

// Round 6
// 234.558 us; speedup vs baseline: 1.1444x; 1.1444x over previous
//
#include <hip/hip_runtime.h>
#include <hip/hip_bf16.h>

#define N_   16
#define CI_  256
#define CO_  256
#define D_   4096
#define DO_  8192
#define KTOT 768            // 3 taps (j outer) x 256 ci
#define XTROWS 4098         // 4096 t + 1 zero pad row each side
#define WT_ELEMS (512 * KTOT)
#define XT_ELEMS ((size_t)N_ * XTROWS * 256)

typedef short frag8 __attribute__((ext_vector_type(8)));   // 8 bf16 (4 VGPR)
typedef float facc4 __attribute__((ext_vector_type(4)));   // 4 f32 acc

static __device__ __forceinline__ unsigned short f2bf(float f) {
    union { __hip_bfloat16 h; unsigned short u; } cv;
    cv.h = __float2bfloat16(f);
    return cv.u;
}

static __device__ __forceinline__ unsigned int pack2(float lo, float hi) {
    return (unsigned int)f2bf(lo) | ((unsigned int)f2bf(hi) << 16);
}

static __device__ __forceinline__ void async16(unsigned short* lds, const unsigned short* g) {
    __builtin_amdgcn_global_load_lds(
        (const __attribute__((address_space(1))) unsigned int*)g,
        (__attribute__((address_space(3))) unsigned int*)lds, 16, 0, 0);
}

// opaque LDS read: no "memory" clobber -> compiler has no alias edge to the
// in-flight global_load_lds writes, so it cannot insert vmcnt(0) drains.
#define DSR_(dst, addr, litstr) \
    asm volatile("ds_read_b128 %0, %1 offset:" litstr : "=&v"(dst) : "v"(addr))

// ---------------- merged prep: weights + x transpose in ONE launch -------
// Blocks x < 128: x [n][ci][t] f32 -> x_t [n][t+1][ci] bf16 (verified r0-r4).
// Blocks x == 128: Wt[m = co*2+phase][k = j*256+ci] effective bf16 weights
// (verified r0-r4); 16 co per y-block.
__global__ __launch_bounds__(256) void prep_all(const float* __restrict__ x,
                                                const float* __restrict__ w,
                                                unsigned short* __restrict__ Wt,
                                                unsigned short* __restrict__ xt) {
    const int tid = threadIdx.x;

    if (blockIdx.x == 128) {
        // ---- prep_wt body: co range [y*16, y*16+16) ----
        const int ci = tid;
        #pragma unroll 2
        for (int i = 0; i < 16; ++i) {
            const int co = blockIdx.y * 16 + i;
            const float* wp = w + ((size_t)co * CI_ + ci) * 3;
            const float w0 = wp[0], w1 = wp[1], w2 = wp[2];
            const float e0 = 0.25f * w1 + 0.75f * w0;
            const float e1 = 0.75f * w2 + 0.75f * w1 + 0.25f * w0;
            const float e2 = 0.25f * w2;
            const float o0 = 0.25f * w0;
            const float o1 = 0.25f * w2 + 0.75f * w1 + 0.75f * w0;
            const float o2 = 0.75f * w2 + 0.25f * w1;
            unsigned short* pe = Wt + (size_t)(co * 2 + 0) * KTOT;
            unsigned short* po = Wt + (size_t)(co * 2 + 1) * KTOT;
            pe[0 * 256 + ci] = f2bf(e0); pe[1 * 256 + ci] = f2bf(e1); pe[2 * 256 + ci] = f2bf(e2);
            po[0 * 256 + ci] = f2bf(o0); po[1 * 256 + ci] = f2bf(o1); po[2 * 256 + ci] = f2bf(o2);
        }
        return;
    }

    // ---- prep_xt2 body (byte-identical logic to verified r0-r4) ----
    __shared__ unsigned int Lp[32][133];   // [t][ci_pair], pitch 133
    const int t0  = blockIdx.x * 32;
    const int n   = blockIdx.y;
    const float* xn = x + (size_t)n * CI_ * D_;
    unsigned short* slab = xt + (size_t)n * XTROWS * 256;

    // zero pad rows (t = -1 and t = 4096), each 512B = 128 u32
    if (t0 == 0 && tid < 128)       ((unsigned int*)slab)[tid] = 0u;
    if (t0 == D_ - 32 && tid < 128) ((unsigned int*)(slab + (size_t)(XTROWS - 1) * 256))[tid] = 0u;

    const int cp_l  = tid >> 3;        // 0..31  (ci-pair within pass)
    const int t_off = (tid & 7) * 4;   // 0,4,...,28

    #pragma unroll
    for (int p = 0; p < 4; ++p) {
        const int ci0 = p * 64 + cp_l * 2;
        float4 a = *(const float4*)(xn + (size_t)ci0 * D_ + t0 + t_off);
        float4 b = *(const float4*)(xn + (size_t)(ci0 + 1) * D_ + t0 + t_off);
        const int cp = p * 32 + cp_l;
        Lp[t_off + 0][cp] = pack2(a.x, b.x);
        Lp[t_off + 1][cp] = pack2(a.y, b.y);
        Lp[t_off + 2][cp] = pack2(a.z, b.z);
        Lp[t_off + 3][cp] = pack2(a.w, b.w);
    }
    __syncthreads();

    // write: 4 iters x 8 rows; 32 lanes x 16B = one full 512B t-row
    #pragma unroll
    for (int it = 0; it < 4; ++it) {
        const int row = it * 8 + (tid >> 5);
        const int c4  = (tid & 31) * 4;           // u32 index within row
        uint4 v;
        v.x = Lp[row][c4 + 0];
        v.y = Lp[row][c4 + 1];
        v.z = Lp[row][c4 + 2];
        v.w = Lp[row][c4 + 3];
        *(uint4*)(slab + (size_t)(1 + t0 + row) * 256 + c4 * 2) = v;
    }
}

// ---------------- main: 256m x 256t 8-phase bf16 MFMA GEMM ---------------
// (byte-identical to round-4 verified kernel, best total 236.1 us)
// C[m][t] = sum_k Wt[m][k] * B[k][t]; B's 768-k column for output row t is
// the CONTIGUOUS 1536B run starting at xt slab row t (3 taps = 3 rows).
// m201-style schedule: K-tile 64, 4 quadrant-phases per K-tile, each phase
// {ds_reads || stage one 16KB half-tile} -> barrier -> lgkm(0) -> 16 MFMA
// -> barrier; stage stream +6 half-tiles ahead; ONE vmcnt(4) per K-tile.
// LDS: A[2dbuf][2mh][2kh][128r][64B] (64KB) then B likewise (64KB) = 128KB.
// Microlayout per [128r][64B] sub-tile: 16B slot XOR by (row>>1)&3
// (verified 0 bank conflicts, rounds 0-4).
__global__ __launch_bounds__(512, 2) void gemm_upfir8(
    const unsigned short* __restrict__ Wt, const unsigned short* __restrict__ xt,
    const float* __restrict__ bias, float* __restrict__ out)
{
    __shared__ __align__(16) unsigned short SL[65536];   // 128 KiB

    const int tid  = threadIdx.x;
    const int lane = tid & 63;
    const int wid  = tid >> 6;          // 0..7
    const int quad = lane >> 4;
    const int l16  = lane & 15;

    const int bt0 = blockIdx.x * 256;   // t tile
    const int bm0 = blockIdx.y * 256;   // m tile (m = co*2+phase)
    const int n   = blockIdx.z;

    // ---- staging addressing (all 8 waves stage every half-tile) ----
    const int srow = wid * 16 + (lane >> 2);            // 0..127 row in half
    const int cg   = (lane & 3) ^ ((lane >> 3) & 3);    // slot-XOR
    const unsigned short* sA = Wt + (size_t)(bm0 + srow) * KTOT + cg * 8;
    const unsigned short* sB = xt + (size_t)n * XTROWS * 256
                                  + (size_t)(bt0 + srow) * 256 + cg * 8;

    // lds stage dests are wave-uniform (ushort offsets; bytes = 2x)
    #define STAGE_A(u, mh) do {                                                     \
        async16(SL + (((u)&1)*16384 + (mh)*8192 + 0*4096 + wid*512),                \
                sA + (size_t)(mh)*128*KTOT + (u)*64 + 0);                           \
        async16(SL + (((u)&1)*16384 + (mh)*8192 + 1*4096 + wid*512),                \
                sA + (size_t)(mh)*128*KTOT + (u)*64 + 32); } while (0)
    #define STAGE_B(u, th) do {                                                     \
        async16(SL + (32768 + ((u)&1)*16384 + (th)*8192 + 0*4096 + wid*512),        \
                sB + (size_t)(th)*128*256 + (u)*64 + 0);                            \
        async16(SL + (32768 + ((u)&1)*16384 + (th)*8192 + 1*4096 + wid*512),        \
                sB + (size_t)(th)*128*256 + (u)*64 + 32); } while (0)

    // ---- fragment read bases (byte addresses) ----
    const int swz = quad ^ ((l16 >> 1) & 3);
    const int mh  = wid & 1;              // wave m-half
    const int wm  = mh * 128;
    const int wt  = ((wid >> 1) & 3) * 64;
    const unsigned base = (unsigned)(size_t)&SL[0];
    const unsigned aB = base + (unsigned)(mh * 16384 + l16 * 64 + swz * 16);
    const unsigned bB = base + 65536u
                      + (unsigned)(((wid >> 2) & 1) * 16384
                                   + (((wid >> 1) & 1) * 64 + l16) * 64 + swz * 16);

    facc4 acc[8][4] = {};

    // ---- prologue: stage half-tiles 0..5 (12 loads/thread) ----
    STAGE_A(0, 0); STAGE_A(0, 1); STAGE_B(0, 0); STAGE_B(0, 1);
    STAGE_A(1, 0); STAGE_A(1, 1);
    asm volatile("s_waitcnt vmcnt(4)" ::: "memory");   // K-tile 0 landed
    __builtin_amdgcn_s_barrier();

    #define MM(m, t)                                                                 \
        acc[m][t] = __builtin_amdgcn_mfma_f32_16x16x32_bf16(a[m][0], b[t][0], acc[m][t], 0, 0, 0); \
        acc[m][t] = __builtin_amdgcn_mfma_f32_16x16x32_bf16(a[m][1], b[t][1], acc[m][t], 0, 0, 0);

    #pragma unroll 2
    for (int u = 0; u < 12; ++u) {
        const unsigned au = aB + (unsigned)((u & 1) << 15);
        const unsigned bu = bB + (unsigned)((u & 1) << 15);
        frag8 a[8][2], b[4][2];

        // ---- Q0: read a[0..3][*], b[0..1][*]; stage B-lo(u+1); MFMA m0-3 x t0-1
        DSR_(a[0][0], au, "0");    DSR_(a[0][1], au, "8192");
        DSR_(a[1][0], au, "1024"); DSR_(a[1][1], au, "9216");
        DSR_(a[2][0], au, "2048"); DSR_(a[2][1], au, "10240");
        DSR_(a[3][0], au, "3072"); DSR_(a[3][1], au, "11264");
        DSR_(b[0][0], bu, "0");    DSR_(b[0][1], bu, "8192");
        DSR_(b[1][0], bu, "1024"); DSR_(b[1][1], bu, "9216");
        if (u < 11) STAGE_B(u + 1, 0);
        __builtin_amdgcn_s_barrier();
        asm volatile("s_waitcnt lgkmcnt(0)" ::: "memory");
        __builtin_amdgcn_sched_barrier(0);
        __builtin_amdgcn_s_setprio(1);
        MM(0, 0) MM(1, 0) MM(2, 0) MM(3, 0)
        MM(0, 1) MM(1, 1) MM(2, 1) MM(3, 1)
        __builtin_amdgcn_s_setprio(0);
        __builtin_amdgcn_s_barrier();

        // ---- Q1: read a[4..7][*]; stage B-hi(u+1); MFMA m4-7 x t0-1
        DSR_(a[4][0], au, "4096"); DSR_(a[4][1], au, "12288");
        DSR_(a[5][0], au, "5120"); DSR_(a[5][1], au, "13312");
        DSR_(a[6][0], au, "6144"); DSR_(a[6][1], au, "14336");
        DSR_(a[7][0], au, "7168"); DSR_(a[7][1], au, "15360");
        if (u < 11) STAGE_B(u + 1, 1);
        __builtin_amdgcn_s_barrier();
        asm volatile("s_waitcnt lgkmcnt(0)" ::: "memory");
        __builtin_amdgcn_sched_barrier(0);
        __builtin_amdgcn_s_setprio(1);
        MM(4, 0) MM(5, 0) MM(6, 0) MM(7, 0)
        MM(4, 1) MM(5, 1) MM(6, 1) MM(7, 1)
        __builtin_amdgcn_s_setprio(0);
        __builtin_amdgcn_s_barrier();

        // ---- Q2: read b[2..3][*]; stage A-lo(u+2); MFMA m4-7 x t2-3
        DSR_(b[2][0], bu, "2048"); DSR_(b[2][1], bu, "10240");
        DSR_(b[3][0], bu, "3072"); DSR_(b[3][1], bu, "11264");
        if (u < 10) STAGE_A(u + 2, 0);
        __builtin_amdgcn_s_barrier();
        asm volatile("s_waitcnt lgkmcnt(0)" ::: "memory");
        __builtin_amdgcn_sched_barrier(0);
        __builtin_amdgcn_s_setprio(1);
        MM(4, 2) MM(5, 2) MM(6, 2) MM(7, 2)
        MM(4, 3) MM(5, 3) MM(6, 3) MM(7, 3)
        __builtin_amdgcn_s_setprio(0);
        __builtin_amdgcn_s_barrier();

        // ---- Q3: no reads; stage A-hi(u+2); MFMA m0-3 x t2-3; vmcnt gate
        if (u < 10) STAGE_A(u + 2, 1);
        __builtin_amdgcn_s_barrier();
        __builtin_amdgcn_sched_barrier(0);
        __builtin_amdgcn_s_setprio(1);
        MM(0, 2) MM(1, 2) MM(2, 2) MM(3, 2)
        MM(0, 3) MM(1, 3) MM(2, 3) MM(3, 3)
        __builtin_amdgcn_s_setprio(0);
        if (u < 10) { asm volatile("s_waitcnt vmcnt(4)" ::: "memory"); }
        else        { asm volatile("s_waitcnt vmcnt(0)" ::: "memory"); }
        __builtin_amdgcn_s_barrier();
    }
    #undef MM
    #undef STAGE_A
    #undef STAGE_B

    // epilogue: D row = quad*4+reg (= m), col = l16 (= t); regs span 2 co x 2 phase
    #pragma unroll
    for (int m8 = 0; m8 < 8; ++m8) {
        int m0  = bm0 + wm + m8 * 16 + quad * 4;
        int co0 = m0 >> 1;
        float b0 = bias[co0];
        float b1 = bias[co0 + 1];
        #pragma unroll
        for (int t4 = 0; t4 < 4; ++t4) {
            int t = bt0 + wt + t4 * 16 + l16;
            facc4 v = acc[m8][t4];
            float* p0 = out + ((size_t)(n * CO_ + co0)) * DO_ + 2 * t;
            float* p1 = p0 + DO_;
            *(float2*)p0 = make_float2(v.x + b0, v.y + b0);
            *(float2*)p1 = make_float2(v.z + b1, v.w + b1);
        }
    }
}

// ---------------- fallback (round-1 verified kernel) ---------------------
__global__ __launch_bounds__(256) void upconv_fir_f32(
    const float* __restrict__ x, const float* __restrict__ w,
    const float* __restrict__ bias, float* __restrict__ out)
{
    __shared__ float ws[CI_][4];
    const int tid = threadIdx.x;
    const int co  = blockIdx.y;
    const int n   = blockIdx.z;
    {
        const float* wc = w + (size_t)co * CI_ * 3;
        ws[tid][0] = wc[tid * 3 + 0];
        ws[tid][1] = wc[tid * 3 + 1];
        ws[tid][2] = wc[tid * 3 + 2];
        ws[tid][3] = 0.f;
    }
    __syncthreads();
    const int t0 = (blockIdx.x * 256 + tid) * 8;
    const float* xn = x + (size_t)n * CI_ * D_;
    float s[10], g[9];
    #pragma unroll
    for (int k = 0; k < 10; ++k) s[k] = 0.f;
    #pragma unroll
    for (int k = 0; k < 9; ++k) g[k] = 0.f;
    #pragma unroll 2
    for (int ci = 0; ci < CI_; ++ci) {
        const float* xr = xn + ci * D_;
        float4 va = *(const float4*)(xr + t0);
        float4 vb = *(const float4*)(xr + t0 + 4);
        float  xm = (t0 > 0)      ? xr[t0 - 1] : 0.f;
        float  xp = (t0 + 8 < D_) ? xr[t0 + 8] : 0.f;
        float4 wv = *(const float4*)(&ws[ci][0]);
        const float w0 = wv.x, w1 = wv.y, w2 = wv.z;
        float xa[10];
        xa[0] = xm; xa[1] = va.x; xa[2] = va.y; xa[3] = va.z; xa[4] = va.w;
        xa[5] = vb.x; xa[6] = vb.y; xa[7] = vb.z; xa[8] = vb.w; xa[9] = xp;
        #pragma unroll
        for (int k = 0; k < 10; ++k) s[k] += w1 * xa[k];
        #pragma unroll
        for (int k = 0; k < 9; ++k)  g[k] += w0 * xa[k] + w2 * xa[k + 1];
    }
    const float b = bias[co];
    float o16[16];
    #pragma unroll
    for (int tt = 0; tt < 8; ++tt) {
        o16[2 * tt]     = 0.25f * (s[tt] + g[tt + 1]) + 0.75f * (g[tt] + s[tt + 1]) + b;
        o16[2 * tt + 1] = 0.25f * (g[tt] + s[tt + 2]) + 0.75f * (s[tt + 1] + g[tt + 1]) + b;
    }
    float* ob = out + ((size_t)n * CO_ + co) * DO_ + 2 * t0;
    *(float4*)(ob + 0)  = make_float4(o16[0],  o16[1],  o16[2],  o16[3]);
    *(float4*)(ob + 4)  = make_float4(o16[4],  o16[5],  o16[6],  o16[7]);
    *(float4*)(ob + 8)  = make_float4(o16[8],  o16[9],  o16[10], o16[11]);
    *(float4*)(ob + 12) = make_float4(o16[12], o16[13], o16[14], o16[15]);
}

extern "C" void kernel_launch(void* const* d_in, const int* in_sizes, int n_in,
                              void* d_out, int out_size, void* d_ws, size_t ws_size,
                              hipStream_t stream) {
    const float* x  = (const float*)d_in[0];
    const float* w  = (const float*)d_in[1];
    const float* b  = (const float*)d_in[2];
    float* out      = (float*)d_out;

    const size_t need = (size_t)WT_ELEMS * 2 + XT_ELEMS * 2;
    if (ws_size >= need) {
        unsigned short* Wt = (unsigned short*)d_ws;
        unsigned short* xt = Wt + WT_ELEMS;
        prep_all<<<dim3(D_ / 32 + 1, N_), 256, 0, stream>>>(x, w, Wt, xt);
        gemm_upfir8<<<dim3(D_ / 256, 2, N_), 512, 0, stream>>>(Wt, xt, b, out);
    } else {
        upconv_fir_f32<<<dim3(2, CO_, N_), 256, 0, stream>>>(x, w, b, out);
    }
}